// Round 1
// baseline (439.196 us; speedup 1.0000x reference)
//
#include <hip/hip_runtime.h>
#include <hip/hip_bf16.h>
#include <math.h>

#define B_    512
#define G_    10
#define T_    100
#define D_    50
#define H_    30
#define NSEQ  10240   // 2*B*G
#define HALF  5120    // B*G
#define EMB_  20
#define NEMB_ 10
#define OUT_  10

// ---------------------------------------------------------------------------
// Kernel A: fused GRU over all 10240 sequences (fp32, VALU).
// grid 2560 x 256. Block = 4 sequences.
// lane: j  = tid&31  (gate row within H, active j<30)
//       kh = (tid>>5)&1 (k-split half of the dot products)
//       s  = tid>>6  (sequence within block; uniform per wave)
// Weights live in VGPRs (126/lane). x and h are read from LDS via broadcast.
// Per step: partial dots -> shfl_xor(32) pair-reduce -> gates -> h update.
// ---------------------------------------------------------------------------
__global__ __launch_bounds__(256) void gru_kernel(
    const float* __restrict__ input1, const float* __restrict__ input2,
    const float* __restrict__ W_ih,  const float* __restrict__ W_hh,
    const float* __restrict__ b_ih,  const float* __restrict__ b_hh,
    float* __restrict__ emb1_out,    // d_out + 5120, [5120][30]
    float* __restrict__ h2_out)      // d_ws, [5120][30]
{
    const int tid = threadIdx.x;
    const int j   = tid & 31;
    const int kh  = (tid >> 5) & 1;
    const int s   = tid >> 6;
    const int blk = blockIdx.x;
    const int n   = blk * 4 + s;
    const bool act = (j < H_);

    // ---- weights into registers (k-split: kh0 -> x[0..23], h[0..15];
    //                              kh1 -> x[24..49], h[16..29]) ----
    const int xb = kh * 24;
    const int hb = kh * 16;
    const int xcnt = kh ? 26 : 24;
    const int hcnt = kh ? 14 : 16;
    float wx[3][26], wh[3][16];
    #pragma unroll
    for (int g = 0; g < 3; ++g) {
        const int row = g * H_ + j;
        #pragma unroll
        for (int k = 0; k < 26; ++k)
            wx[g][k] = (act && k < xcnt) ? W_ih[row * D_ + xb + k] : 0.f;
        #pragma unroll
        for (int k = 0; k < 16; ++k)
            wh[g][k] = (act && k < hcnt) ? W_hh[row * H_ + hb + k] : 0.f;
    }
    const float bias_r  = (act && !kh) ? b_ih[j]        + b_hh[j]        : 0.f;
    const float bias_z  = (act && !kh) ? b_ih[H_ + j]   + b_hh[H_ + j]   : 0.f;
    const float bias_ni = (act && !kh) ? b_ih[2*H_ + j]                  : 0.f;
    const float bias_nh = (act && !kh) ? b_hh[2*H_ + j]                  : 0.f;

    __shared__ float Xs[2][4][4][52];   // [buf][seq][t-in-chunk][50 pad 52]
    __shared__ float Hs[4][32];         // [seq][30 pad 32]
    if (tid < 128) Hs[tid >> 5][tid & 31] = 0.f;   // h0 = 0 (+ zero padding)

    // ---- x staging: chunk of 4 timesteps = 200 contiguous dwords per seq,
    //      800 dwords per block = 400 float2 over 256 lanes (1..2 each) ----
    const int ii0 = tid, ii1 = tid + 256;
    const int sa = ii0 / 100, da = (ii0 % 100) * 2;
    const int sb = ii1 / 100, db = (ii1 % 100) * 2;
    const int na = blk * 4 + sa, nb = blk * 4 + sb;
    const float* srcA = (na < HALF ? input1 + (size_t)na * (T_*D_)
                                   : input2 + (size_t)(na - HALF) * (T_*D_)) + da;
    const float* srcB = (nb < HALF ? input1 + (size_t)nb * (T_*D_)
                                   : input2 + (size_t)(nb - HALF) * (T_*D_)) + db;
    const int tta = da / 50, ka = da % 50;
    const int ttb = db / 50, kb = db % 50;
    const bool stB = (ii1 < 400);

    // prologue: stage chunk 0 into buf 0
    {
        float2 pa = *(const float2*)(srcA);
        *(float2*)&Xs[0][sa][tta][ka] = pa;
        if (stB) {
            float2 pb = *(const float2*)(srcB);
            *(float2*)&Xs[0][sb][ttb][kb] = pb;
        }
    }
    __syncthreads();

    float hnew = 0.f;
    #pragma unroll 1
    for (int c = 0; c < 25; ++c) {
        const int buf = c & 1;
        // prefetch next chunk into registers (written to LDS at tt==3)
        float2 pa = make_float2(0.f, 0.f), pb = make_float2(0.f, 0.f);
        if (c < 24) {
            pa = *(const float2*)(srcA + (c + 1) * 200);
            if (stB) pb = *(const float2*)(srcB + (c + 1) * 200);
        }
        #pragma unroll
        for (int tt = 0; tt < 4; ++tt) {
            // ---- read x / h chunks (LDS broadcast within 32-lane groups) ----
            float xv[26];
            const float* xrow = &Xs[buf][s][tt][xb];
            #pragma unroll
            for (int q = 0; q < 6; ++q)
                *(float4*)&xv[q * 4] = *(const float4*)(xrow + q * 4);
            *(float2*)&xv[24] = *(const float2*)(xrow + 24);
            float hv[16];
            const float* hrow = &Hs[s][hb];
            #pragma unroll
            for (int q = 0; q < 4; ++q)
                *(float4*)&hv[q * 4] = *(const float4*)(hrow + q * 4);
            const float h_old = Hs[s][j];

            // ---- partial dots ----
            float ar = bias_r, az = bias_z, ani = bias_ni, anh = bias_nh;
            #pragma unroll
            for (int k = 0; k < 26; ++k) {
                ar  += wx[0][k] * xv[k];
                az  += wx[1][k] * xv[k];
                ani += wx[2][k] * xv[k];
            }
            #pragma unroll
            for (int k = 0; k < 16; ++k) {
                ar  += wh[0][k] * hv[k];
                az  += wh[1][k] * hv[k];
                anh += wh[2][k] * hv[k];
            }
            // ---- pair reduce across kh halves ----
            ar  += __shfl_xor(ar, 32);
            az  += __shfl_xor(az, 32);
            ani += __shfl_xor(ani, 32);
            anh += __shfl_xor(anh, 32);

            // ---- gates (PyTorch GRU: r, z, n) ----
            const float r = 1.f / (1.f + __expf(-ar));
            const float z = 1.f / (1.f + __expf(-az));
            const float a = ani + r * anh;
            const float nn = 1.f - 2.f / (__expf(2.f * a) + 1.f);   // tanh(a)
            hnew = nn + z * (h_old - nn);

            __syncthreads();                       // all reads of old h done
            if (kh == 0 && act) Hs[s][j] = hnew;
            if (tt == 3 && c < 24) {               // publish next x chunk
                *(float2*)&Xs[buf ^ 1][sa][tta][ka] = pa;
                if (stB) *(float2*)&Xs[buf ^ 1][sb][ttb][kb] = pb;
            }
            __syncthreads();                       // writes visible
        }
    }

    // ---- final hidden state out ----
    if (kh == 0 && act) {
        if (n < HALF) emb1_out[n * H_ + j] = hnew;                 // embeddings1
        else          h2_out[(n - HALF) * H_ + j] = hnew;          // MLP input
    }
}

// ---------------------------------------------------------------------------
// Kernel B: tiny MLP head. grid 512 x 64; one row (batch element) per block.
// logit = gelu(gelu(e2 @ W1^T + b1) @ W2^T + b2) @ W3^T + b3   (exact gelu)
// ---------------------------------------------------------------------------
__global__ __launch_bounds__(64) void mlp_kernel(
    const float* __restrict__ h2,   // [512][300]
    const float* __restrict__ W1, const float* __restrict__ b1,
    const float* __restrict__ W2, const float* __restrict__ b2,
    const float* __restrict__ W3, const float* __restrict__ b3,
    float* __restrict__ logit)      // [512][10]
{
    const int b    = blockIdx.x;
    const int lane = threadIdx.x;
    __shared__ float e2[300];
    const float* row = h2 + (size_t)b * 300;
    #pragma unroll
    for (int i = lane; i < 75; i += 64)
        *(float4*)&e2[i * 4] = *(const float4*)(row + i * 4);
    __syncthreads();

    const float kInvSqrt2 = 0.70710678118654752f;
    float y1 = 0.f;
    if (lane < EMB_) {
        float acc = b1[lane];
        const float* w = W1 + lane * 300;
        #pragma unroll
        for (int q = 0; q < 75; ++q) {
            float4 wv = *(const float4*)(w + q * 4);
            acc += wv.x * e2[q*4 + 0] + wv.y * e2[q*4 + 1]
                 + wv.z * e2[q*4 + 2] + wv.w * e2[q*4 + 3];
        }
        y1 = 0.5f * acc * (1.f + erff(acc * kInvSqrt2));   // exact gelu
    }
    float acc2 = (lane < NEMB_) ? b2[lane] : 0.f;
    #pragma unroll
    for (int e = 0; e < EMB_; ++e) {
        const float v = __shfl(y1, e);
        if (lane < NEMB_) acc2 += v * W2[lane * EMB_ + e];
    }
    const float y2 = 0.5f * acc2 * (1.f + erff(acc2 * kInvSqrt2));
    float acc3 = (lane < OUT_) ? b3[lane] : 0.f;
    #pragma unroll
    for (int e = 0; e < NEMB_; ++e) {
        const float v = __shfl(y2, e);
        if (lane < OUT_) acc3 += v * W3[lane * NEMB_ + e];
    }
    if (lane < OUT_) logit[(size_t)b * OUT_ + lane] = acc3;
}

// ---------------------------------------------------------------------------
extern "C" void kernel_launch(void* const* d_in, const int* in_sizes, int n_in,
                              void* d_out, int out_size, void* d_ws, size_t ws_size,
                              hipStream_t stream) {
    const float* input1 = (const float*)d_in[0];
    const float* input2 = (const float*)d_in[1];
    const float* W_ih   = (const float*)d_in[2];
    const float* W_hh   = (const float*)d_in[3];
    const float* b_ih   = (const float*)d_in[4];
    const float* b_hh   = (const float*)d_in[5];
    const float* W1     = (const float*)d_in[6];
    const float* b1     = (const float*)d_in[7];
    const float* W2     = (const float*)d_in[8];
    const float* b2     = (const float*)d_in[9];
    const float* W3     = (const float*)d_in[10];
    const float* b3     = (const float*)d_in[11];

    float* out = (float*)d_out;                 // [5120 logit][153600 emb1]
    float* h2  = (float*)d_ws;                  // 5120*30 floats = 614.4 KB

    hipLaunchKernelGGL(gru_kernel, dim3(2560), dim3(256), 0, stream,
                       input1, input2, W_ih, W_hh, b_ih, b_hh,
                       out + 5120, h2);
    hipLaunchKernelGGL(mlp_kernel, dim3(512), dim3(64), 0, stream,
                       h2, W1, b1, W2, b2, W3, b3, out);
}

// Round 2
// 224.889 us; speedup vs baseline: 1.9529x; 1.9529x over previous
//
#include <hip/hip_runtime.h>
#include <hip/hip_bf16.h>
#include <math.h>

#define B_    512
#define G_    10
#define T_    100
#define D_    50
#define H_    30
#define HALF  5120
#define EMB_  20
#define NEMB_ 10
#define OUT_  10

typedef _Float16 h2 __attribute__((ext_vector_type(2)));
union F4H { float4 f; h2 h[4]; };

// ---------------------------------------------------------------------------
// GRU: one wave per sequence, 4 waves (4 seqs) per block, NO barriers.
// lane = j (gate row, 30 of 32) + 32*kh (k-split half).
// Weights in f16-pair VGPRs; dots via v_dot2_f32_f16 (fp32 accumulate).
// x staged per-wave in LDS as f16 (10-step chunks, double buffered, register
// prefetch); h kept in a wave-private LDS row (f16) + fp32 register h_old.
// ---------------------------------------------------------------------------
__global__ __launch_bounds__(256) void gru_kernel(
    const float* __restrict__ input1, const float* __restrict__ input2,
    const float* __restrict__ W_ih,  const float* __restrict__ W_hh,
    const float* __restrict__ b_ih,  const float* __restrict__ b_hh,
    float* __restrict__ emb1_out,    // [5120][30]
    float* __restrict__ h2_out)      // [5120][30]
{
    const int tid  = threadIdx.x;
    const int lane = tid & 63;
    const int j    = tid & 31;
    const int kh   = (tid >> 5) & 1;
    const int w    = tid >> 6;              // wave id == seq within block
    const int n    = blockIdx.x * 4 + w;
    const bool act = (j < H_);

    __shared__ __align__(16) _Float16 Xs[4][2][10][56];  // [wave][buf][t][50 pad 56]
    __shared__ __align__(16) _Float16 Hs[4][32];         // [wave][30 pad 32]

    // ---- k-split: kh0 -> x halves 0..23, h halves 0..15
    //              kh1 -> x halves 24..49, h halves 16..29 ----
    const int xb  = kh ? 24 : 0;
    const int hb  = kh ? 16 : 0;
    const int nxp = kh ? 13 : 12;   // valid f16 pairs in x-path
    const int nhp = kh ? 7  : 8;    // valid f16 pairs in h-path

    h2 wxp[3][13];
    h2 whp[3][8];
    #pragma unroll
    for (int g = 0; g < 3; ++g) {
        const int row = g * H_ + j;
        #pragma unroll
        for (int p = 0; p < 13; ++p) {
            float a = 0.f, b = 0.f;
            if (act && p < nxp) {
                a = W_ih[row * D_ + xb + 2 * p];
                b = W_ih[row * D_ + xb + 2 * p + 1];
            }
            h2 v = {(_Float16)a, (_Float16)b};
            wxp[g][p] = v;
        }
        #pragma unroll
        for (int p = 0; p < 8; ++p) {
            float a = 0.f, b = 0.f;
            if (act && p < nhp) {
                a = W_hh[row * H_ + hb + 2 * p];
                b = W_hh[row * H_ + hb + 2 * p + 1];
            }
            h2 v = {(_Float16)a, (_Float16)b};
            whp[g][p] = v;
        }
    }
    const float bias_r  = (act && !kh) ? b_ih[j]          + b_hh[j]          : 0.f;
    const float bias_z  = (act && !kh) ? b_ih[H_ + j]     + b_hh[H_ + j]     : 0.f;
    const float bias_ni = (act && !kh) ? b_ih[2 * H_ + j]                    : 0.f;
    const float bias_nh = (act && !kh) ? b_hh[2 * H_ + j]                    : 0.f;

    // ---- wave-private x staging: chunk = 10 steps = 500 floats = 250 h2 ----
    const float* src = (n < HALF) ? input1 + (size_t)n * (T_ * D_)
                                  : input2 + (size_t)(n - HALF) * (T_ * D_);
    const int i0 = lane, i1 = lane + 64, i2 = lane + 128, i3 = lane + 192;
    const int o0 = (i0 / 25) * 56 + 2 * (i0 % 25);
    const int o1 = (i1 / 25) * 56 + 2 * (i1 % 25);
    const int o2 = (i2 / 25) * 56 + 2 * (i2 % 25);
    const int o3 = (i3 / 25) * 56 + 2 * (i3 % 25);
    const bool m3 = (lane < 58);            // 250 = 3*64 + 58
    _Float16* XB = &Xs[w][0][0][0];         // buf stride = 560 halves

    // prologue: stage chunk 0 into buf 0; zero h row
    {
        float2 p0 = *(const float2*)(src + 2 * i0);
        float2 p1 = *(const float2*)(src + 2 * i1);
        float2 p2 = *(const float2*)(src + 2 * i2);
        float2 p3 = make_float2(0.f, 0.f);
        if (m3) p3 = *(const float2*)(src + 2 * i3);
        h2 c0 = {(_Float16)p0.x, (_Float16)p0.y}; *(h2*)(XB + o0) = c0;
        h2 c1 = {(_Float16)p1.x, (_Float16)p1.y}; *(h2*)(XB + o1) = c1;
        h2 c2 = {(_Float16)p2.x, (_Float16)p2.y}; *(h2*)(XB + o2) = c2;
        if (m3) { h2 c3 = {(_Float16)p3.x, (_Float16)p3.y}; *(h2*)(XB + o3) = c3; }
    }
    if (!kh && j < 16) {
        h2 zz = {(_Float16)0.f, (_Float16)0.f};
        *(h2*)(&Hs[w][0] + 2 * j) = zz;     // h0 = 0 (incl. pad halves 30,31)
    }

    float h_old = 0.f;
    #pragma unroll 1
    for (int c = 0; c < 10; ++c) {
        _Float16* Xcur = XB + (c & 1) * 560;
        _Float16* Xnxt = XB + ((c & 1) ^ 1) * 560;
        float2 q0 = make_float2(0.f, 0.f), q1 = q0, q2 = q0, q3 = q0;
        const bool pre = (c < 9);
        if (pre) {                           // register prefetch of next chunk
            const float* s2 = src + (c + 1) * (10 * D_);
            q0 = *(const float2*)(s2 + 2 * i0);
            q1 = *(const float2*)(s2 + 2 * i1);
            q2 = *(const float2*)(s2 + 2 * i2);
            if (m3) q3 = *(const float2*)(s2 + 2 * i3);
        }
        #pragma unroll
        for (int tt = 0; tt < 10; ++tt) {
            F4H xr[4];
            const float4* xrow = (const float4*)(Xcur + tt * 56 + xb);
            xr[0].f = xrow[0]; xr[1].f = xrow[1];
            xr[2].f = xrow[2]; xr[3].f = xrow[3];
            F4H hr[2];
            const float4* hrow = (const float4*)(&Hs[w][0] + hb);
            hr[0].f = hrow[0]; hr[1].f = hrow[1];

            float ar  = bias_r,  az  = bias_z,  ani = bias_ni;
            float ar2 = 0.f,     az2 = 0.f,     anh = bias_nh;
            #pragma unroll
            for (int p = 0; p < 13; ++p) {
                h2 xv = xr[p >> 2].h[p & 3];
                ar  = __builtin_amdgcn_fdot2(wxp[0][p], xv, ar,  false);
                az  = __builtin_amdgcn_fdot2(wxp[1][p], xv, az,  false);
                ani = __builtin_amdgcn_fdot2(wxp[2][p], xv, ani, false);
            }
            #pragma unroll
            for (int p = 0; p < 8; ++p) {
                h2 hv = hr[p >> 2].h[p & 3];
                ar2 = __builtin_amdgcn_fdot2(whp[0][p], hv, ar2, false);
                az2 = __builtin_amdgcn_fdot2(whp[1][p], hv, az2, false);
                anh = __builtin_amdgcn_fdot2(whp[2][p], hv, anh, false);
            }
            ar += ar2; az += az2;
            ar  += __shfl_xor(ar, 32);
            az  += __shfl_xor(az, 32);
            ani += __shfl_xor(ani, 32);
            anh += __shfl_xor(anh, 32);

            const float r  = __builtin_amdgcn_rcpf(1.f + __expf(-ar));
            const float z  = __builtin_amdgcn_rcpf(1.f + __expf(-az));
            const float aa = fmaf(r, anh, ani);
            const float t  = fmaf(-2.f, __builtin_amdgcn_rcpf(1.f + __expf(2.f * aa)), 1.f);
            h_old = fmaf(z, h_old - t, t);   // (1-z)*t + z*h_old
            if (!kh && act) Hs[w][j] = (_Float16)h_old;
        }
        if (pre) {                           // publish next chunk
            h2 c0 = {(_Float16)q0.x, (_Float16)q0.y}; *(h2*)(Xnxt + o0) = c0;
            h2 c1 = {(_Float16)q1.x, (_Float16)q1.y}; *(h2*)(Xnxt + o1) = c1;
            h2 c2 = {(_Float16)q2.x, (_Float16)q2.y}; *(h2*)(Xnxt + o2) = c2;
            if (m3) { h2 c3 = {(_Float16)q3.x, (_Float16)q3.y}; *(h2*)(Xnxt + o3) = c3; }
        }
    }

    if (!kh && act) {
        if (n < HALF) emb1_out[n * H_ + j] = h_old;
        else          h2_out[(n - HALF) * H_ + j] = h_old;
    }
}

// ---------------------------------------------------------------------------
// MLP head (unchanged): one row per block.
// ---------------------------------------------------------------------------
__global__ __launch_bounds__(64) void mlp_kernel(
    const float* __restrict__ h2i,  // [512][300]
    const float* __restrict__ W1, const float* __restrict__ b1,
    const float* __restrict__ W2, const float* __restrict__ b2,
    const float* __restrict__ W3, const float* __restrict__ b3,
    float* __restrict__ logit)      // [512][10]
{
    const int b    = blockIdx.x;
    const int lane = threadIdx.x;
    __shared__ float e2[300];
    const float* row = h2i + (size_t)b * 300;
    #pragma unroll
    for (int i = lane; i < 75; i += 64)
        *(float4*)&e2[i * 4] = *(const float4*)(row + i * 4);
    __syncthreads();

    const float kInvSqrt2 = 0.70710678118654752f;
    float y1 = 0.f;
    if (lane < EMB_) {
        float acc = b1[lane];
        const float* wp = W1 + lane * 300;
        #pragma unroll
        for (int q = 0; q < 75; ++q) {
            float4 wv = *(const float4*)(wp + q * 4);
            acc += wv.x * e2[q*4 + 0] + wv.y * e2[q*4 + 1]
                 + wv.z * e2[q*4 + 2] + wv.w * e2[q*4 + 3];
        }
        y1 = 0.5f * acc * (1.f + erff(acc * kInvSqrt2));
    }
    float acc2 = (lane < NEMB_) ? b2[lane] : 0.f;
    #pragma unroll
    for (int e = 0; e < EMB_; ++e) {
        const float v = __shfl(y1, e);
        if (lane < NEMB_) acc2 += v * W2[lane * EMB_ + e];
    }
    const float y2 = 0.5f * acc2 * (1.f + erff(acc2 * kInvSqrt2));
    float acc3 = (lane < OUT_) ? b3[lane] : 0.f;
    #pragma unroll
    for (int e = 0; e < NEMB_; ++e) {
        const float v = __shfl(y2, e);
        if (lane < OUT_) acc3 += v * W3[lane * NEMB_ + e];
    }
    if (lane < OUT_) logit[(size_t)b * OUT_ + lane] = acc3;
}

// ---------------------------------------------------------------------------
extern "C" void kernel_launch(void* const* d_in, const int* in_sizes, int n_in,
                              void* d_out, int out_size, void* d_ws, size_t ws_size,
                              hipStream_t stream) {
    const float* input1 = (const float*)d_in[0];
    const float* input2 = (const float*)d_in[1];
    const float* W_ih   = (const float*)d_in[2];
    const float* W_hh   = (const float*)d_in[3];
    const float* b_ih   = (const float*)d_in[4];
    const float* b_hh   = (const float*)d_in[5];
    const float* W1     = (const float*)d_in[6];
    const float* b1     = (const float*)d_in[7];
    const float* W2     = (const float*)d_in[8];
    const float* b2     = (const float*)d_in[9];
    const float* W3     = (const float*)d_in[10];
    const float* b3     = (const float*)d_in[11];

    float* out = (float*)d_out;                 // [5120 logit][153600 emb1]
    float* h2s = (float*)d_ws;                  // 5120*30 floats

    hipLaunchKernelGGL(gru_kernel, dim3(2560), dim3(256), 0, stream,
                       input1, input2, W_ih, W_hh, b_ih, b_hh,
                       out + 5120, h2s);
    hipLaunchKernelGGL(mlp_kernel, dim3(512), dim3(64), 0, stream,
                       h2s, W1, b1, W2, b2, W3, b3, out);
}

// Round 4
// 122.647 us; speedup vs baseline: 3.5810x; 1.8336x over previous
//
#include <hip/hip_runtime.h>
#include <hip/hip_bf16.h>
#include <math.h>

#define B_    512
#define T_    100
#define D_    50
#define H_    30
#define HALF  5120
#define EMB_  20
#define NEMB_ 10
#define OUT_  10

typedef _Float16 h2    __attribute__((ext_vector_type(2)));
typedef _Float16 f16x8 __attribute__((ext_vector_type(8)));
typedef float    f32x4 __attribute__((ext_vector_type(4)));

union FR  { f16x8 v; h2 p[4]; float4 f4; };
union PK2 { h2 h[2]; float2 f2; };

// v_cvt_pkrtz_f16_f32 wrapper: builtin returns __fp16x2; bit-cast to our h2.
__device__ __forceinline__ h2 pk(float a, float b) {
    return __builtin_bit_cast(h2, __builtin_amdgcn_cvt_pkrtz(a, b));
}

// W LDS [96 rows][64 cols] f16: swizzle so frag ds_read_b128 (row=l&15,
// col=(l>>4)*8) is conflict-free: half-index col ^= (row&7)<<3.
__device__ __forceinline__ int swzW(int r, int c) { return r * 64 + (c ^ ((r & 7) << 3)); }
// Xw LDS [96 gates][16 t] f16: swizzle t ^= ((g>>2)&3)<<2 -> conflict-free
// b64 writes (4 t per lane) AND conflict-free per-step u16 reads (30 lanes).
__device__ __forceinline__ int swzX(int g, int t) { return g * 16 + (t ^ (((g >> 2) & 3) << 2)); }

// ---------------------------------------------------------------------------
// GRU: block = 256 threads = 4 waves = 8 sequences (2 per wave, one per
// 32-lane half). Per 16-step chunk: xw = x @ W_ih^T via 24 MFMA into LDS
// (b_ih folded via x[d=50]=1 trick), then 16 serial steps of the h-recurrence
// with 45 dot2/wave serving both sequences. No shuffles, one barrier total.
// ---------------------------------------------------------------------------
__global__ __launch_bounds__(256) void gru_kernel(
    const float* __restrict__ input1, const float* __restrict__ input2,
    const float* __restrict__ W_ih,  const float* __restrict__ W_hh,
    const float* __restrict__ b_ih,  const float* __restrict__ b_hh,
    float* __restrict__ emb1_out,    // [5120][30]
    float* __restrict__ h2_out)      // [5120][30]
{
    const int tid  = threadIdx.x;
    const int lane = tid & 63;
    const int w    = tid >> 6;          // wave 0..3
    const int lr   = lane & 15;         // frag row
    const int lq   = lane >> 4;         // frag quad 0..3
    const int hs   = lane >> 5;         // which seq of the wave
    const int jj   = lane & 31;         // gate row 0..31 (30 active)
    const bool act = (jj < H_);
    const int slot = w * 2 + hs;        // seq slot in block 0..7
    const int n    = blockIdx.x * 8 + slot;

    __shared__ __align__(16) _Float16 Wl[96 * 64];    // 12 KB
    __shared__ __align__(16) _Float16 Xw[8][96 * 16]; // 24 KB
    __shared__ __align__(16) _Float16 Hs[8][32];      // 0.5 KB

    // ---- stage W_ih (+ b_ih at col 50) into Wl, swizzled ----
    #pragma unroll
    for (int i = 0; i < 12; ++i) {
        int pidx = tid + i * 256;            // 0..3071 h2-pairs
        int g  = pidx >> 5;
        int c0 = (pidx & 31) * 2;
        float va = 0.f, vb = 0.f;
        if (g < 90) {
            va = (c0     < 50) ? W_ih[g * 50 + c0]     : (c0     == 50 ? b_ih[g] : 0.f);
            vb = (c0 + 1 < 50) ? W_ih[g * 50 + c0 + 1] : (c0 + 1 == 50 ? b_ih[g] : 0.f);
        }
        *(h2*)&Wl[swzW(g, c0)] = pk(va, vb);
    }

    // ---- h-path weights into registers (15 h2 x 3 gates) ----
    h2 whp[3][15];
    {
        const int jw = act ? jj : 0;
        #pragma unroll
        for (int g = 0; g < 3; ++g) {
            const float* wr = W_hh + (size_t)(g * H_ + jw) * H_;
            #pragma unroll
            for (int p = 0; p < 15; ++p) {
                float2 t = *(const float2*)(wr + 2 * p);
                whp[g][p] = pk(t.x, t.y);
            }
        }
    }
    const float bhr = act ? b_hh[jj]       : 0.f;
    const float bhz = act ? b_hh[H_ + jj]  : 0.f;
    const float bhn = act ? b_hh[2*H_ + jj]: 0.f;

    // ---- this wave's two sequence base pointers ----
    const int n0 = blockIdx.x * 8 + w * 2;
    const float* srcp[2];
    srcp[0] = (n0     < HALF) ? input1 + (size_t)n0 * (T_*D_)
                              : input2 + (size_t)(n0 - HALF) * (T_*D_);
    srcp[1] = (n0 + 1 < HALF) ? input1 + (size_t)(n0 + 1) * (T_*D_)
                              : input2 + (size_t)(n0 + 1 - HALF) * (T_*D_);

    if (jj < 16) {                      // h0 = 0 (both halves init their slot)
        h2 zz = pk(0.f, 0.f);
        *(h2*)&Hs[slot][2 * jj] = zz;
    }
    __syncthreads();                    // Wl ready

    _Float16* XwS  = &Xw[slot][0];
    _Float16* Hrow = &Hs[slot][0];
    // precomputed swizzled Xw read bases for the 3 gates of row jj
    const int xr_b = jj * 16,        xr_x = ((jj >> 2) & 3) << 2;
    const int xz_b = (30 + jj) * 16, xz_x = (((30 + jj) >> 2) & 3) << 2;
    const int xn_b = (60 + jj) * 16, xn_x = (((60 + jj) >> 2) & 3) << 2;

    float hreg = 0.f;
    #pragma unroll 1
    for (int c = 0; c < 7; ++c) {
        // ---- A-fragments direct from global (fp32 -> f16), K padded to 64,
        //      d=50 -> 1.0 (bias), d>50 -> 0, rows t>=100 clamped (unread) ----
        FR af[2][2];
        #pragma unroll
        for (int s = 0; s < 2; ++s) {
            int t = c * 16 + lr; if (t > 99) t = 99;
            const float* rp = srcp[s] + (size_t)t * D_;
            float2 q0[4], q1[4];
            #pragma unroll
            for (int e = 0; e < 4; ++e)
                q0[e] = *(const float2*)(rp + lq * 8 + 2 * e);
            if (lq < 2) {
                #pragma unroll
                for (int e = 0; e < 4; ++e)
                    q1[e] = *(const float2*)(rp + 32 + lq * 8 + 2 * e);
            } else if (lq == 2) {
                q1[0] = *(const float2*)(rp + 48);
                q1[1] = make_float2(1.f, 0.f);       // d=50 bias column
                q1[2] = make_float2(0.f, 0.f);
                q1[3] = make_float2(0.f, 0.f);
            } else {
                #pragma unroll
                for (int e = 0; e < 4; ++e) q1[e] = make_float2(0.f, 0.f);
            }
            #pragma unroll
            for (int e = 0; e < 4; ++e) {
                af[s][0].p[e] = pk(q0[e].x, q0[e].y);
                af[s][1].p[e] = pk(q1[e].x, q1[e].y);
            }
        }
        // ---- xw chunk via MFMA: [16 t][96 gates] for each of 2 seqs ----
        #pragma unroll
        for (int s = 0; s < 2; ++s) {
            _Float16* xwd = &Xw[w * 2 + s][0];
            #pragma unroll
            for (int nt = 0; nt < 6; ++nt) {
                FR b0, b1;
                b0.f4 = *(const float4*)&Wl[swzW(nt * 16 + lr, lq * 8)];
                b1.f4 = *(const float4*)&Wl[swzW(nt * 16 + lr, 32 + lq * 8)];
                f32x4 acc = {0.f, 0.f, 0.f, 0.f};
                acc = __builtin_amdgcn_mfma_f32_16x16x32_f16(af[s][0].v, b0.v, acc, 0, 0, 0);
                acc = __builtin_amdgcn_mfma_f32_16x16x32_f16(af[s][1].v, b1.v, acc, 0, 0, 0);
                // C: col g = nt*16 + (l&15), rows t = lq*4 + reg (4 consecutive)
                PK2 o;
                o.h[0] = pk(acc[0], acc[1]);
                o.h[1] = pk(acc[2], acc[3]);
                *(float2*)&xwd[swzX(nt * 16 + lr, lq * 4)] = o.f2;
            }
        }
        // ---- serial recurrence over this chunk ----
        const int nst = (c == 6) ? 4 : 16;
        #pragma unroll 4
        for (int tt = 0; tt < nst; ++tt) {
            const float xwr = (float)XwS[xr_b + (tt ^ xr_x)];
            const float xwz = (float)XwS[xz_b + (tt ^ xz_x)];
            const float xwn = (float)XwS[xn_b + (tt ^ xn_x)];
            FR hr[4];
            #pragma unroll
            for (int q = 0; q < 4; ++q) hr[q].f4 = ((const float4*)Hrow)[q];

            float sr0 = bhr, sz0 = bhz, sn0 = bhn;
            float sr1 = 0.f, sz1 = 0.f, sn1 = 0.f;
            #pragma unroll
            for (int p = 0; p < 8; ++p) {
                h2 hv = hr[p >> 2].p[p & 3];
                sr0 = __builtin_amdgcn_fdot2(whp[0][p], hv, sr0, false);
                sz0 = __builtin_amdgcn_fdot2(whp[1][p], hv, sz0, false);
                sn0 = __builtin_amdgcn_fdot2(whp[2][p], hv, sn0, false);
            }
            #pragma unroll
            for (int p = 8; p < 15; ++p) {
                h2 hv = hr[p >> 2].p[p & 3];
                sr1 = __builtin_amdgcn_fdot2(whp[0][p], hv, sr1, false);
                sz1 = __builtin_amdgcn_fdot2(whp[1][p], hv, sz1, false);
                sn1 = __builtin_amdgcn_fdot2(whp[2][p], hv, sn1, false);
            }
            const float ar  = xwr + sr0 + sr1;
            const float az  = xwz + sz0 + sz1;
            const float anh = sn0 + sn1;
            const float r  = __builtin_amdgcn_rcpf(1.f + __expf(-ar));
            const float z  = __builtin_amdgcn_rcpf(1.f + __expf(-az));
            const float aa = fmaf(r, anh, xwn);
            const float th = fmaf(-2.f, __builtin_amdgcn_rcpf(1.f + __expf(2.f * aa)), 1.f);
            hreg = fmaf(z, hreg - th, th);
            Hrow[jj] = (_Float16)hreg;    // pad cols 30,31 absorb inactive lanes
        }
    }

    if (act) {
        if (n < HALF) emb1_out[n * H_ + jj] = hreg;
        else          h2_out[(n - HALF) * H_ + jj] = hreg;
    }
}

// ---------------------------------------------------------------------------
// MLP head (unchanged): one row per block.
// ---------------------------------------------------------------------------
__global__ __launch_bounds__(64) void mlp_kernel(
    const float* __restrict__ h2i,  // [512][300]
    const float* __restrict__ W1, const float* __restrict__ b1,
    const float* __restrict__ W2, const float* __restrict__ b2,
    const float* __restrict__ W3, const float* __restrict__ b3,
    float* __restrict__ logit)      // [512][10]
{
    const int b    = blockIdx.x;
    const int lane = threadIdx.x;
    __shared__ float e2[300];
    const float* row = h2i + (size_t)b * 300;
    #pragma unroll
    for (int i = lane; i < 75; i += 64)
        *(float4*)&e2[i * 4] = *(const float4*)(row + i * 4);
    __syncthreads();

    const float kInvSqrt2 = 0.70710678118654752f;
    float y1 = 0.f;
    if (lane < EMB_) {
        float acc = b1[lane];
        const float* wp = W1 + lane * 300;
        #pragma unroll
        for (int q = 0; q < 75; ++q) {
            float4 wv = *(const float4*)(wp + q * 4);
            acc += wv.x * e2[q*4 + 0] + wv.y * e2[q*4 + 1]
                 + wv.z * e2[q*4 + 2] + wv.w * e2[q*4 + 3];
        }
        y1 = 0.5f * acc * (1.f + erff(acc * kInvSqrt2));
    }
    float acc2 = (lane < NEMB_) ? b2[lane] : 0.f;
    #pragma unroll
    for (int e = 0; e < EMB_; ++e) {
        const float v = __shfl(y1, e);
        if (lane < NEMB_) acc2 += v * W2[lane * EMB_ + e];
    }
    const float y2 = 0.5f * acc2 * (1.f + erff(acc2 * kInvSqrt2));
    float acc3 = (lane < OUT_) ? b3[lane] : 0.f;
    #pragma unroll
    for (int e = 0; e < NEMB_; ++e) {
        const float v = __shfl(y2, e);
        if (lane < OUT_) acc3 += v * W3[lane * NEMB_ + e];
    }
    if (lane < OUT_) logit[(size_t)b * OUT_ + lane] = acc3;
}

// ---------------------------------------------------------------------------
extern "C" void kernel_launch(void* const* d_in, const int* in_sizes, int n_in,
                              void* d_out, int out_size, void* d_ws, size_t ws_size,
                              hipStream_t stream) {
    const float* input1 = (const float*)d_in[0];
    const float* input2 = (const float*)d_in[1];
    const float* W_ih   = (const float*)d_in[2];
    const float* W_hh   = (const float*)d_in[3];
    const float* b_ih   = (const float*)d_in[4];
    const float* b_hh   = (const float*)d_in[5];
    const float* W1     = (const float*)d_in[6];
    const float* b1     = (const float*)d_in[7];
    const float* W2     = (const float*)d_in[8];
    const float* b2     = (const float*)d_in[9];
    const float* W3     = (const float*)d_in[10];
    const float* b3     = (const float*)d_in[11];

    float* out = (float*)d_out;                 // [5120 logit][153600 emb1]
    float* h2s = (float*)d_ws;                  // 5120*30 floats

    hipLaunchKernelGGL(gru_kernel, dim3(1280), dim3(256), 0, stream,
                       input1, input2, W_ih, W_hh, b_ih, b_hh,
                       out + 5120, h2s);
    hipLaunchKernelGGL(mlp_kernel, dim3(512), dim3(64), 0, stream,
                       h2s, W1, b1, W2, b2, W3, b3, out);
}